// Round 1
// 204.983 us; speedup vs baseline: 1.0691x; 1.0691x over previous
//
#include <hip/hip_runtime.h>
#include <cstdint>
#include <cstddef>

#define BB   4
#define CIN  64
#define VV   50000
#define COUT 128
#define NV   32            // vertices per block
#define KTOT 448           // CIN*7, kk = k*64 + c
#define KT   14            // KTOT/32 MFMA k-steps
#define PITCH 456          // G LDS row pitch in fp16 elems (448+8)

typedef __attribute__((ext_vector_type(8))) short    short8;
typedef __attribute__((ext_vector_type(8))) _Float16 half8;
typedef __attribute__((ext_vector_type(4))) _Float16 half4;
typedef __attribute__((ext_vector_type(4))) float    f32x4;

// Static device buffers (no ws_size dependence). Rewritten every launch.
__device__ _Float16       g_xt[(size_t)BB * VV * CIN];   // x transposed [b][v][c], fp16, 25.6 MB
__device__ unsigned short g_wb[KT * 8 * 64 * 8];         // W in MFMA A-frag order (fp16 bits), 114 KB

__device__ inline unsigned short f2h(float f) {
    union { _Float16 h; unsigned short u; } cv;
    cv.h = (_Float16)f;
    return cv.u;
}

// ---------------------------------------------------------------------------
// Transpose x[B][C][V] (fp32) -> g_xt[B][V][C] (fp16).
// Read: thread (tc=t>>4, tv=t&15) loads float4 along v for c = tc+16i.
// Write: thread (c8=t&7, tvv=t>>3) stores 8 fp16 (16 B) along c for
// v = v0 + tvv + 32i. LDS tile[64][65]: both phases <=2-way aliasing (free).
// ---------------------------------------------------------------------------
__global__ __launch_bounds__(256) void transpose_k(const float* __restrict__ x) {
    __shared__ float tile[64][65];
    int b  = blockIdx.y;
    int v0 = blockIdx.x * 64;
    int t  = threadIdx.x;
    int tv = t & 15;    // v4-group: v = v0 + tv*4 .. +3
    int tc = t >> 4;    // c = tc + 16*i
#pragma unroll
    for (int i = 0; i < 4; i++) {
        int c = tc + 16 * i;
        int v = v0 + tv * 4;
        const float* src = x + ((size_t)b * CIN + c) * VV + v;
        float4 f;
        if (v + 3 < VV) {
            f = *(const float4*)src;
        } else {
            f.x = v + 0 < VV ? src[0] : 0.f;
            f.y = v + 1 < VV ? src[1] : 0.f;
            f.z = v + 2 < VV ? src[2] : 0.f;
            f.w = v + 3 < VV ? src[3] : 0.f;
        }
        tile[c][tv * 4 + 0] = f.x;
        tile[c][tv * 4 + 1] = f.y;
        tile[c][tv * 4 + 2] = f.z;
        tile[c][tv * 4 + 3] = f.w;
    }
    __syncthreads();
    int c8  = t & 7;    // c = c8*8 .. +7
    int tvv = t >> 3;   // v = v0 + tvv + 32*i
#pragma unroll
    for (int i = 0; i < 2; i++) {
        int v = v0 + tvv + 32 * i;
        if (v < VV) {
            union { _Float16 h[8]; short8 s; } u;
#pragma unroll
            for (int j = 0; j < 8; j++)
                u.h[j] = (_Float16)tile[c8 * 8 + j][tvv + 32 * i];
            *(short8*)(g_xt + ((size_t)b * VV + v) * CIN + c8 * 8) = u.s;
        }
    }
}

// ---------------------------------------------------------------------------
// Pack W[o][c][k] (fp32) into fp16 MFMA A-fragments:
//   g_wb[(kt*8 + mt)*64 + lane][j] = W_fp16[m = mt*16 + (lane&15)]
//                                     [kk = kt*32 + (lane>>4)*8 + j], kk=k*64+c
// ---------------------------------------------------------------------------
__global__ __launch_bounds__(256) void pack_wb_k(const float* __restrict__ W) {
    int idx = blockIdx.x * 256 + threadIdx.x;   // over KT*8*64 = 7168
    if (idx >= KT * 8 * 64) return;
    int lane = idx & 63;
    int mt   = (idx >> 6) & 7;
    int kt   = idx >> 9;
    int m    = mt * 16 + (lane & 15);
    int kb   = kt * 32 + (lane >> 4) * 8;
    union { unsigned short s[8]; short8 v; } u;
#pragma unroll
    for (int j = 0; j < 8; j++) {
        int kk = kb + j;
        int c  = kk & 63;
        int k  = kk >> 6;
        u.s[j] = f2h(W[((size_t)m * CIN + c) * 7 + k]);
    }
    *(short8*)&g_wb[(size_t)idx * 8] = u.v;
}

__device__ inline void feats(float f0, float f1, float f2, float f3, float* g) {
    g[0] = f0;
    g[1] = f1 + f2 + f3;
    float p12 = f1 * f2, p13 = f1 * f3, p23 = f2 * f3;
    g[2] = p12 * f3;
    g[3] = p12 + p13 + p23;
    g[4] = f1 * f1 + f2 * f2 + f3 * f3;
    g[5] = fabsf(f1 - f2) + fabsf(f1 - f3) + fabsf(f2 - f3);
    g[6] = f1 * f1 * f1 + f2 * f2 * f2 + f3 * f3 * f3;
}

// ---------------------------------------------------------------------------
// Main kernel. Block = (batch b, 32-vertex tile).
//  Phase 0: stage 32x4 neighbor indices into LDS.
//  Phase 1: batched gather (8 independent 8B fp16 loads per thread in flight),
//           7 symmetric features per channel, ds_write_b64 into G[32][PITCH].
//  Phase 2: 4 waves x (2m x 2n) mfma_f32_16x16x32_f16; A from g_wb (global,
//           coalesced, L2-resident), B via ds_read_b128.
// ---------------------------------------------------------------------------
__global__ __launch_bounds__(256) void mesh_k(
        const void* __restrict__ Gi, const float* __restrict__ bias,
        float* __restrict__ out) {
    __shared__ _Float16 Gl[NV * PITCH];   // 28.5 KB
    __shared__ int Sidx[NV][4];           // 512 B

    int b  = blockIdx.y;
    int v0 = blockIdx.x * NV;
    int t  = threadIdx.x;

    // Gi dtype sniff (int64 vs int32); wave-uniform.
    const unsigned* gu = (const unsigned*)Gi;
    bool is64 = ((gu[1] | gu[3] | gu[5] | gu[7]) == 0u);

    // ---- Phase 0: stage indices ----
    if (t < NV * 4) {
        int vv = t >> 2, j = t & 3;
        int v  = v0 + vv;
        long long val = 0;
        if (v < VV) {
            size_t gb = ((size_t)b * VV + v) * 4 + j;
            val = is64 ? ((const long long*)Gi)[gb] : (long long)((const int*)Gi)[gb];
        }
        Sidx[vv][j] = (int)(val < 0 ? 0 : (val >= VV ? VV - 1 : val));
    }
    __syncthreads();

    // ---- Phase 1: batched gather + features ----
    int c4   = t & 15;   // channels 4*c4 .. 4*c4+3
    int slot = t >> 4;   // vertex slots: slot, slot+16
    int J[2][4];
#pragma unroll
    for (int p = 0; p < 2; ++p) {
        int vv = slot + p * 16;
#pragma unroll
        for (int j = 0; j < 4; ++j) J[p][j] = Sidx[vv][j];
    }
    const _Float16* base = g_xt + (size_t)b * VV * CIN + c4 * 4;
    half4 F[2][4];
#pragma unroll
    for (int p = 0; p < 2; ++p)
#pragma unroll
        for (int j = 0; j < 4; ++j)
            F[p][j] = *(const half4*)(base + (size_t)J[p][j] * CIN);

#pragma unroll
    for (int p = 0; p < 2; ++p) {
        int vv = slot + p * 16;
        float gc[4][7];
#pragma unroll
        for (int i = 0; i < 4; ++i)
            feats((float)F[p][0][i], (float)F[p][1][i],
                  (float)F[p][2][i], (float)F[p][3][i], gc[i]);
        _Float16* grow = &Gl[vv * PITCH + c4 * 4];   // feature k at elem k*64
#pragma unroll
        for (int k = 0; k < 7; k++) {
            union { _Float16 h[4]; half4 v; } u;
#pragma unroll
            for (int i = 0; i < 4; ++i) u.h[i] = (_Float16)gc[i][k];
            *(half4*)(grow + k * 64) = u.v;   // ds_write_b64, 4 dwords/bank (min)
        }
        // v >= VV tail: garbage column, never stored (GEMM columns independent)
    }
    __syncthreads();

    // ---- Phase 2: MFMA ----
    int w    = t >> 6;    // wave id: m rows 32w..32w+31
    int lane = t & 63;
    int l15  = lane & 15;
    int q    = lane >> 4;

    f32x4 acc[2][2] = {};

    const half8* wb = (const half8*)g_wb;
#pragma unroll 2
    for (int kt = 0; kt < KT; ++kt) {
        half8 a0 = wb[(kt * 8 + 2 * w    ) * 64 + lane];
        half8 a1 = wb[(kt * 8 + 2 * w + 1) * 64 + lane];
        half8 b0 = *(const half8*)&Gl[(l15     ) * PITCH + kt * 32 + q * 8];
        half8 b1 = *(const half8*)&Gl[(l15 + 16) * PITCH + kt * 32 + q * 8];
        acc[0][0] = __builtin_amdgcn_mfma_f32_16x16x32_f16(a0, b0, acc[0][0], 0, 0, 0);
        acc[0][1] = __builtin_amdgcn_mfma_f32_16x16x32_f16(a0, b1, acc[0][1], 0, 0, 0);
        acc[1][0] = __builtin_amdgcn_mfma_f32_16x16x32_f16(a1, b0, acc[1][0], 0, 0, 0);
        acc[1][1] = __builtin_amdgcn_mfma_f32_16x16x32_f16(a1, b1, acc[1][1], 0, 0, 0);
    }

    // ---- Epilogue: D col=lane&15 (v), row=(lane>>4)*4+reg (o) ----
#pragma unroll
    for (int mt = 0; mt < 2; ++mt) {
        int o = 32 * w + mt * 16 + q * 4;
        float bs[4];
#pragma unroll
        for (int r = 0; r < 4; ++r) bs[r] = bias[o + r];
#pragma unroll
        for (int nt = 0; nt < 2; ++nt) {
            int v = v0 + nt * 16 + l15;
            if (v < VV) {
                float* po = out + ((size_t)b * COUT + o) * VV + v;
#pragma unroll
                for (int r = 0; r < 4; ++r)
                    po[(size_t)r * VV] = acc[mt][nt][r] + bs[r];
            }
        }
    }
}

// ---------------------------------------------------------------------------
extern "C" void kernel_launch(void* const* d_in, const int* in_sizes, int n_in,
                              void* d_out, int out_size, void* d_ws, size_t ws_size,
                              hipStream_t stream) {
    const float* x    = (const float*)d_in[0];
    const void*  Gi   = d_in[1];
    const float* W    = (const float*)d_in[2];
    const float* bias = (const float*)d_in[3];
    float* out        = (float*)d_out;

    dim3 gt((VV + 63) / 64, BB);
    transpose_k<<<gt, 256, 0, stream>>>(x);
    pack_wb_k<<<(KT * 8 * 64 + 255) / 256, 256, 0, stream>>>(W);
    dim3 gm((VV + NV - 1) / NV, BB);
    mesh_k<<<gm, 256, 0, stream>>>(Gi, bias, out);
}

// Round 2
// 197.475 us; speedup vs baseline: 1.1097x; 1.0380x over previous
//
#include <hip/hip_runtime.h>
#include <cstdint>
#include <cstddef>

#define BB   4
#define CIN  64
#define VV   50000
#define COUT 128
#define NV   32            // vertices per block
#define KTOT 448           // CIN*7, kk = k*64 + c
#define KT   14            // KTOT/32 MFMA k-steps
#define PITCH 456          // G LDS row pitch in fp16 elems (448+8)

typedef __attribute__((ext_vector_type(8))) short    short8;
typedef __attribute__((ext_vector_type(8))) _Float16 half8;
typedef __attribute__((ext_vector_type(4))) float    f32x4;

// Static device buffers (no ws_size dependence). Rewritten every launch.
__device__ _Float16       g_xt[(size_t)BB * VV * CIN];   // x transposed [b][v][c], fp16, 25.6 MB
__device__ unsigned short g_wb[KT * 8 * 64 * 8];         // W in MFMA A-frag order (fp16 bits), 114 KB

__device__ inline unsigned short f2h(float f) {
    union { _Float16 h; unsigned short u; } cv;
    cv.h = (_Float16)f;
    return cv.u;
}

// ---------------------------------------------------------------------------
// Transpose x[B][C][V] (fp32) -> g_xt[B][V][C] (fp16), with the W pack fused
// into the first 28 blocks of batch 0.
// x is read exactly once -> nontemporal loads (keep L3 for g_xt, which mesh_k
// will re-read randomly). g_xt writes stay cached on purpose.
// ---------------------------------------------------------------------------
__global__ __launch_bounds__(256) void transpose_k(const float* __restrict__ x,
                                                   const float* __restrict__ W) {
    // ---- fused weight pack: W[o][c][k] fp32 -> fp16 MFMA A-fragments ----
    //   g_wb[(kt*8 + mt)*64 + lane][j] = W_fp16[m = mt*16 + (lane&15)]
    //                                     [kk = kt*32 + (lane>>4)*8 + j]
    if (blockIdx.y == 0 && blockIdx.x < (KT * 8 * 64 + 255) / 256) {
        int idx = blockIdx.x * 256 + threadIdx.x;   // over KT*8*64 = 7168
        if (idx < KT * 8 * 64) {
            int lane = idx & 63;
            int mt   = (idx >> 6) & 7;
            int kt   = idx >> 9;
            int m    = mt * 16 + (lane & 15);
            int kb   = kt * 32 + (lane >> 4) * 8;
            union { unsigned short s[8]; short8 v; } u;
#pragma unroll
            for (int j = 0; j < 8; j++) {
                int kk = kb + j;
                int c  = kk & 63;
                int k  = kk >> 6;
                u.s[j] = f2h(W[((size_t)m * CIN + c) * 7 + k]);
            }
            *(short8*)&g_wb[(size_t)idx * 8] = u.v;
        }
    }

    __shared__ float tile[64][65];
    int b  = blockIdx.y;
    int v0 = blockIdx.x * 64;
    int t  = threadIdx.x;
    int tv = t & 15;    // v4-group: v = v0 + tv*4 .. +3
    int tc = t >> 4;    // c = tc + 16*i
#pragma unroll
    for (int i = 0; i < 4; i++) {
        int c = tc + 16 * i;
        int v = v0 + tv * 4;
        const float* src = x + ((size_t)b * CIN + c) * VV + v;
        f32x4 f;
        if (v + 3 < VV) {
            f = __builtin_nontemporal_load((const f32x4*)src);
        } else {
            f[0] = v + 0 < VV ? src[0] : 0.f;
            f[1] = v + 1 < VV ? src[1] : 0.f;
            f[2] = v + 2 < VV ? src[2] : 0.f;
            f[3] = v + 3 < VV ? src[3] : 0.f;
        }
        tile[c][tv * 4 + 0] = f[0];
        tile[c][tv * 4 + 1] = f[1];
        tile[c][tv * 4 + 2] = f[2];
        tile[c][tv * 4 + 3] = f[3];
    }
    __syncthreads();
    int c8  = t & 7;    // c = c8*8 .. +7
    int tvv = t >> 3;   // v = v0 + tvv + 32*i
#pragma unroll
    for (int i = 0; i < 2; i++) {
        int v = v0 + tvv + 32 * i;
        if (v < VV) {
            union { _Float16 h[8]; short8 s; } u;
#pragma unroll
            for (int j = 0; j < 8; j++)
                u.h[j] = (_Float16)tile[c8 * 8 + j][tvv + 32 * i];
            *(short8*)(g_xt + ((size_t)b * VV + v) * CIN + c8 * 8) = u.s;
        }
    }
}

__device__ inline void feats(float f0, float f1, float f2, float f3, float* g) {
    g[0] = f0;
    g[1] = f1 + f2 + f3;
    float p12 = f1 * f2, p13 = f1 * f3, p23 = f2 * f3;
    g[2] = p12 * f3;
    g[3] = p12 + p13 + p23;
    g[4] = f1 * f1 + f2 * f2 + f3 * f3;
    g[5] = fabsf(f1 - f2) + fabsf(f1 - f3) + fabsf(f2 - f3);
    g[6] = f1 * f1 * f1 + f2 * f2 * f2 + f3 * f3 * f3;
}

// ---------------------------------------------------------------------------
// Main kernel. Block = (batch b, 32-vertex tile).
//  Phase 0: stage 32x4 neighbor indices into LDS (nt loads: Gi read once).
//  Phase 1: batched gather: thread = (8 channels, 1 vertex slot), 4 x 16B
//           independent loads in flight; 7 symmetric features for 8 channels;
//           7 x ds_write_b128 into G[32][PITCH] (min-aliasing banks).
//  Phase 2: 4 waves x (2m x 2n) mfma_f32_16x16x32_f16; A from g_wb (global,
//           coalesced, L2-resident), B via ds_read_b128.
//  Epilogue: nontemporal stores (out never re-read; keep L3 for g_xt).
// ---------------------------------------------------------------------------
__global__ __launch_bounds__(256) void mesh_k(
        const void* __restrict__ Gi, const float* __restrict__ bias,
        float* __restrict__ out) {
    __shared__ _Float16 Gl[NV * PITCH];   // 28.5 KB
    __shared__ int Sidx[NV][4];           // 512 B

    int b  = blockIdx.y;
    int v0 = blockIdx.x * NV;
    int t  = threadIdx.x;

    // Gi dtype sniff (int64 vs int32); wave-uniform.
    const unsigned* gu = (const unsigned*)Gi;
    bool is64 = ((gu[1] | gu[3] | gu[5] | gu[7]) == 0u);

    // ---- Phase 0: stage indices ----
    if (t < NV * 4) {
        int vv = t >> 2, j = t & 3;
        int v  = v0 + vv;
        long long val = 0;
        if (v < VV) {
            size_t gb = ((size_t)b * VV + v) * 4 + j;
            val = is64 ? __builtin_nontemporal_load((const long long*)Gi + gb)
                       : (long long)__builtin_nontemporal_load((const int*)Gi + gb);
        }
        Sidx[vv][j] = (int)(val < 0 ? 0 : (val >= VV ? VV - 1 : val));
    }
    __syncthreads();

    // ---- Phase 1: batched gather + features ----
    int c8   = t & 7;    // channels 8*c8 .. 8*c8+7
    int slot = t >> 3;   // vertex slot 0..31
    int J[4];
#pragma unroll
    for (int j = 0; j < 4; ++j) J[j] = Sidx[slot][j];

    const _Float16* base = g_xt + (size_t)b * VV * CIN + c8 * 8;
    half8 F[4];
#pragma unroll
    for (int j = 0; j < 4; ++j)
        F[j] = *(const half8*)(base + (size_t)J[j] * CIN);

    union { _Float16 h[8]; short8 s; } u[7];
#pragma unroll
    for (int i = 0; i < 8; ++i) {
        float g7[7];
        feats((float)F[0][i], (float)F[1][i], (float)F[2][i], (float)F[3][i], g7);
#pragma unroll
        for (int k = 0; k < 7; ++k) u[k].h[i] = (_Float16)g7[k];
    }
    _Float16* grow = &Gl[slot * PITCH + c8 * 8];   // feature k at elem k*64
#pragma unroll
    for (int k = 0; k < 7; ++k)
        *(short8*)(grow + k * 64) = u[k].s;        // ds_write_b128
    // v >= VV tail: garbage column, never stored (GEMM columns independent)
    __syncthreads();

    // ---- Phase 2: MFMA ----
    int w    = t >> 6;    // wave id: m rows 32w..32w+31
    int lane = t & 63;
    int l15  = lane & 15;
    int q    = lane >> 4;

    f32x4 acc[2][2] = {};

    const half8* wb = (const half8*)g_wb;
#pragma unroll 2
    for (int kt = 0; kt < KT; ++kt) {
        half8 a0 = wb[(kt * 8 + 2 * w    ) * 64 + lane];
        half8 a1 = wb[(kt * 8 + 2 * w + 1) * 64 + lane];
        half8 b0 = *(const half8*)&Gl[(l15     ) * PITCH + kt * 32 + q * 8];
        half8 b1 = *(const half8*)&Gl[(l15 + 16) * PITCH + kt * 32 + q * 8];
        acc[0][0] = __builtin_amdgcn_mfma_f32_16x16x32_f16(a0, b0, acc[0][0], 0, 0, 0);
        acc[0][1] = __builtin_amdgcn_mfma_f32_16x16x32_f16(a0, b1, acc[0][1], 0, 0, 0);
        acc[1][0] = __builtin_amdgcn_mfma_f32_16x16x32_f16(a1, b0, acc[1][0], 0, 0, 0);
        acc[1][1] = __builtin_amdgcn_mfma_f32_16x16x32_f16(a1, b1, acc[1][1], 0, 0, 0);
    }

    // ---- Epilogue: D col=lane&15 (v), row=(lane>>4)*4+reg (o); nt stores ----
#pragma unroll
    for (int mt = 0; mt < 2; ++mt) {
        int o = 32 * w + mt * 16 + q * 4;
        float bs[4];
#pragma unroll
        for (int r = 0; r < 4; ++r) bs[r] = bias[o + r];
#pragma unroll
        for (int n = 0; n < 2; ++n) {
            int v = v0 + n * 16 + l15;
            if (v < VV) {
                float* po = out + ((size_t)b * COUT + o) * VV + v;
#pragma unroll
                for (int r = 0; r < 4; ++r)
                    __builtin_nontemporal_store(acc[mt][n][r] + bs[r], po + (size_t)r * VV);
            }
        }
    }
}

// ---------------------------------------------------------------------------
extern "C" void kernel_launch(void* const* d_in, const int* in_sizes, int n_in,
                              void* d_out, int out_size, void* d_ws, size_t ws_size,
                              hipStream_t stream) {
    const float* x    = (const float*)d_in[0];
    const void*  Gi   = d_in[1];
    const float* W    = (const float*)d_in[2];
    const float* bias = (const float*)d_in[3];
    float* out        = (float*)d_out;

    dim3 gt((VV + 63) / 64, BB);
    transpose_k<<<gt, 256, 0, stream>>>(x, W);
    dim3 gm((VV + NV - 1) / NV, BB);
    mesh_k<<<gm, 256, 0, stream>>>(Gi, bias, out);
}